// Round 3
// baseline (13368.582 us; speedup 1.0000x reference)
//
#include <hip/hip_runtime.h>
#include <stdint.h>
#include <stddef.h>

// Problem constants
#define NB 256
#define NT 512
#define NH 256
#define NZT 64
#define BN_EPS 1e-5f

// d_out offsets (floats)
#define OUT_SC    0
#define OUT_SCAT  2048
#define OUT_TC    4608
#define OUT_TCAT  2101760
#define OUT_MASK  3281408

// workspace offsets (floats)
#define WS_BL1    0
#define WS_BASE   65536
#define WS_BIAS   131072     // bias2 [256][768] (includes bhh for o<512)
#define WS_HHIST  327680     // h history [B][T][H] = 33,554,432 floats
#define WS_HAZ    33882112   // hazard [B*T][2]
#define WS_BFRAG  34144256   // B fragments (ushort), 491,520 ushorts
// total ≈ 34,390,016 floats ≈ 131.2 MiB

typedef __bf16 bf16x8 __attribute__((ext_vector_type(8)));
typedef float f32x4v __attribute__((ext_vector_type(4)));

// ---------------- threefry2x32 (JAX constants, 20 rounds) ----------------
__host__ __device__ inline void tf2x32(uint32_t k0, uint32_t k1, uint32_t& x0, uint32_t& x1) {
  uint32_t k2 = k0 ^ k1 ^ 0x1BD11BDAu;
#define RR(d) { x0 += x1; x1 = (x1 << d) | (x1 >> (32 - d)); x1 ^= x0; }
  x0 += k0; x1 += k1;
  RR(13) RR(15) RR(26) RR(6)  x0 += k1; x1 += k2 + 1u;
  RR(17) RR(29) RR(16) RR(24) x0 += k2; x1 += k0 + 2u;
  RR(13) RR(15) RR(26) RR(6)  x0 += k0; x1 += k1 + 3u;
  RR(17) RR(29) RR(16) RR(24) x0 += k1; x1 += k2 + 4u;
  RR(13) RR(15) RR(26) RR(6)  x0 += k2; x1 += k0 + 5u;
#undef RR
}

// partitionable-mode random bits for 32-bit draws: block (0, idx), bits = x0^x1
__device__ inline float gumbel_pt(uint32_t k0, uint32_t k1, uint32_t idx) {
  uint32_t x0 = 0u, x1 = idx;
  tf2x32(k0, k1, x0, x1);
  uint32_t bits = x0 ^ x1;
  uint32_t fb = (bits >> 9) | 0x3F800000u;
  float f = __uint_as_float(fb) - 1.0f;            // [0,1)
  const float TINY = 1.17549435e-38f;
  f = f * (1.0f - TINY) + TINY;                    // uniform(minval=tiny, maxval=1)
  f = fmaxf(TINY, f);
  return -logf(-logf(f));
}

// ---------------- bf16 split helpers (RNE) ----------------
__device__ inline uint16_t f2bf(float v) {
  uint32_t u = __float_as_uint(v);
  u += 0x7FFFu + ((u >> 16) & 1u);
  return (uint16_t)(u >> 16);
}
__device__ inline float bf2f(uint16_t h) { return __uint_as_float(((uint32_t)h) << 16); }

__device__ inline f32x4v mfma16(bf16x8 a, bf16x8 b, f32x4v c) {
  return __builtin_amdgcn_mfma_f32_16x16x32_bf16(a, b, c, 0, 0, 0);
}

// ---------------- prep: build B fragments (bf16 hi/lo, MFMA layout) ----
// Bfrag layout: [ot(48)][ks(10)][part(2)][lane(64)][8]  (16B per lane item)
// element: k = ks*32 + (lane>>4)*8 + j ; o = ot*16 + (lane&15)
// B[k][o] = (k<256) ? whh[o][k] : wih[o][k-256]   (z_t occupies wih cols 0..63)
__global__ void k_prep(const float* __restrict__ whh, const float* __restrict__ wih,
                       uint16_t* __restrict__ bfrag) {
  int gid = blockIdx.x * 256 + threadIdx.x;   // grid 240 x 256 = 61440
  if (gid >= 61440) return;
  int l = gid & 63;
  int rest = gid >> 6;
  int part = rest & 1; rest >>= 1;
  int ks = rest % 10, ot = rest / 10;
  uint16_t outv[8];
#pragma unroll
  for (int j = 0; j < 8; ++j) {
    int k = ks * 32 + (l >> 4) * 8 + j;
    int o = ot * 16 + (l & 15);
    float v = (k < 256) ? whh[o * 256 + k] : wih[o * 325 + (k - 256)];
    uint16_t hi = f2bf(v);
    outv[j] = (part == 0) ? hi : f2bf(v - bf2f(hi));
  }
  *(uint4*)(bfrag + (size_t)gid * 8) = *(uint4*)outv;
}

// ---------------- static layer: relu(x@W^T+b) then BatchNorm (batch stats) ----
__global__ void k_static(const float* __restrict__ x, int K, const float* __restrict__ w,
                         const float* __restrict__ bias, const float* __restrict__ g,
                         const float* __restrict__ bb, float* __restrict__ out) {
  int c = blockIdx.x, r = threadIdx.x;
  const float* wr = w + c * K;              // wave-uniform -> s_loads
  float acc = bias[c];
  for (int k = 0; k < K; ++k) acc += x[r * K + k] * wr[k];
  float v = fmaxf(acc, 0.0f);
  __shared__ float red[256];
  red[r] = v; __syncthreads();
  for (int s = 128; s > 0; s >>= 1) { if (r < s) red[r] += red[r + s]; __syncthreads(); }
  float m = red[0] * (1.0f / 256.0f);
  __syncthreads();
  float d = v - m;
  red[r] = d * d; __syncthreads();
  for (int s = 128; s > 0; s >>= 1) { if (r < s) red[r] += red[r + s]; __syncthreads(); }
  float var = red[0] * (1.0f / 256.0f);
  out[r * NH + c] = d * rsqrtf(var + BN_EPS) * g[c] + bb[c];
}

// ------- bias2[b][o] = bih[o] + baseline[b]·wih[o,64:320] + init·wih[o,321:325]
//         + (o<512 ? bhh[o] : 0)    (visit term handled per-step)
__global__ void k_bias(const float* __restrict__ baseline, const float* __restrict__ init,
                       const float* __restrict__ wih, const float* __restrict__ bih,
                       const float* __restrict__ bhh, float* __restrict__ bias2) {
  int b = blockIdx.x, tid = threadIdx.x;
  __shared__ float bl[256];
  __shared__ float in4[4];
  bl[tid] = baseline[b * 256 + tid];
  if (tid < 4) in4[tid] = init[b * 4 + tid];
  __syncthreads();
  for (int oo = 0; oo < 3; ++oo) {
    int o = oo * 256 + tid;
    const float* wr = wih + (size_t)o * 325;
    float acc = bih[o];
    for (int k = 0; k < 256; ++k) acc += bl[k] * wr[64 + k];
#pragma unroll
    for (int i = 0; i < 4; ++i) acc += in4[i] * wr[321 + i];
    if (o < 512) acc += bhh[o];
    bias2[b * 768 + o] = acc;
  }
}

// ---------------- static heads: static_cont + gumbel-softmax static_cat ----------
__global__ void k_sheads(const float* __restrict__ baseline, const float* __restrict__ sc_w,
                         const float* __restrict__ sc_b, const float* __restrict__ s1w,
                         const float* __restrict__ s1b, const float* __restrict__ s2w,
                         const float* __restrict__ s2b, float* __restrict__ out,
                         uint32_t g0a, uint32_t g0b, uint32_t g1a, uint32_t g1b) {
  int b = blockIdx.x, tid = threadIdx.x;   // 64 threads
  __shared__ float bl[256];
  __shared__ float lg[10];
  for (int i = tid; i < 256; i += 64) bl[i] = baseline[b * 256 + i];
  __syncthreads();
  if (tid < 18) {
    const float* wr; float bias;
    if (tid < 8)       { wr = sc_w + tid * 256;        bias = sc_b[tid]; }
    else if (tid < 12) { wr = s1w + (tid - 8) * 256;   bias = s1b[tid - 8]; }
    else               { wr = s2w + (tid - 12) * 256;  bias = s2b[tid - 12]; }
    float acc = bias;
    for (int k = 0; k < 256; ++k) acc += bl[k] * wr[k];
    if (tid < 8)       out[OUT_SC + b * 8 + tid] = tanhf(acc) * 0.5f + 0.5f;
    else if (tid < 12) lg[tid - 8] = acc + gumbel_pt(g0a, g0b, (uint32_t)(b * 4 + (tid - 8)));
    else               lg[tid - 8] = acc + gumbel_pt(g1a, g1b, (uint32_t)(b * 6 + (tid - 12)));
  }
  __syncthreads();
  if (tid == 0) {
    float m = fmaxf(fmaxf(lg[0], lg[1]), fmaxf(lg[2], lg[3]));
    float e[4], s = 0.f;
    for (int i = 0; i < 4; ++i) { e[i] = expf(lg[i] - m); s += e[i]; }
    float* o1 = out + OUT_SCAT + b * 10;
    for (int i = 0; i < 4; ++i) o1[i] = e[i] / s;
  } else if (tid == 1) {
    float m = lg[4];
    for (int i = 5; i < 10; ++i) m = fmaxf(m, lg[i]);
    float e[6], s = 0.f;
    for (int i = 0; i < 6; ++i) { e[i] = expf(lg[4 + i] - m); s += e[i]; }
    float* o1 = out + OUT_SCAT + b * 10 + 4;
    for (int i = 0; i < 6; ++i) o1[i] = e[i] / s;
  }
}

// ---------------- persistent GRU: 16 blocks x 256 threads, all 512 steps --------
// Block bb owns batch rows [bb*16, bb*16+16). 4 waves; wave w owns h cols
// [w*64, w*64+64) (q-tiles jt=w*4+q) and the matching r/z/n gate tiles.
// B tiering per step: ks 0..1 from REGISTERS (preloaded, 192 VGPR/wave),
// ks 2..9 streamed from L2 (768 KB/block/step). bf16x3 split throughout.
__global__ __launch_bounds__(256, 1)
void k_persist(const float* __restrict__ zt, const uint16_t* __restrict__ bfrag,
               const float* __restrict__ bias2, const float* __restrict__ wih,
               const float* __restrict__ bhh, float* __restrict__ h_hist) {
  int bb = blockIdx.x;
  int tid = threadIdx.x;
  int w = tid >> 6, lane = tid & 63;
  int l15 = lane & 15, l4 = lane >> 4;

  __shared__ __align__(16) uint16_t afr[10][2][64][8];   // A fragments hi/lo (20 KB)
  __shared__ __align__(16) float hbuf[16][260];          // h state f32 (16.6 KB)

  // zero h0
  for (int i = tid; i < 16 * 260; i += 256) ((float*)hbuf)[i] = 0.0f;

  // ---- register-resident B tier: ks 0,1 for this wave's 12 ot tiles ----
  // oti = g*4 + q  ->  ot = g*16 + w*4 + q
  bf16x8 Brg[2][12][2];   // [ks][oti][part] = 48 frags = 192 VGPRs
#pragma unroll
  for (int oti = 0; oti < 12; ++oti) {
    int ot = (oti >> 2) * 16 + w * 4 + (oti & 3);
    const uint16_t* p = bfrag + (size_t)ot * 10240 + lane * 8;
    Brg[0][oti][0] = *(const bf16x8*)(p);
    Brg[0][oti][1] = *(const bf16x8*)(p + 512);
    Brg[1][oti][0] = *(const bf16x8*)(p + 1024);
    Brg[1][oti][1] = *(const bf16x8*)(p + 1536);
  }

  // cache per-lane epilogue constants (same addresses every step)
  float b2r[4][4], b2z[4][4], b2x[4][4], bhn4[4], wvr[4], wvz[4], wvn[4];
#pragma unroll
  for (int q = 0; q < 4; ++q) {
    int j = (w * 4 + q) * 16 + l15;
    wvr[q] = wih[(size_t)j * 325 + 320];
    wvz[q] = wih[(size_t)(256 + j) * 325 + 320];
    wvn[q] = wih[(size_t)(512 + j) * 325 + 320];
    bhn4[q] = bhh[512 + j];
#pragma unroll
    for (int r = 0; r < 4; ++r) {
      int brow = bb * 16 + l4 * 4 + r;
      b2r[q][r] = bias2[brow * 768 + j];
      b2z[q][r] = bias2[brow * 768 + 256 + j];
      b2x[q][r] = bias2[brow * 768 + 512 + j];
    }
  }

  // z prefetch: thread owns z[b = tid>>4][ (tid&15)*4 .. +4 ] for each t
  const float* zbase = zt + (size_t)(bb * 16 + (tid >> 4)) * NT * NZT + (tid & 15) * 4;
  float4 zv = *(const float4*)zbase;   // t = 0

  const uint16_t* baseB = bfrag + (size_t)lane * 8;

  __syncthreads();

#pragma unroll 1
  for (int t = 0; t < NT; ++t) {
    // ---- stage A fragments: h part (ks 0..7) from hbuf, z part (ks 8,9) from zv
#pragma unroll
    for (int i = 0; i < 2; ++i) {
      int it = tid + i * 256;            // 0..511
      int b = it >> 5, k8 = it & 31;
      float4 v0 = *(const float4*)&hbuf[b][k8 * 8];
      float4 v1 = *(const float4*)&hbuf[b][k8 * 8 + 4];
      float v[8] = {v0.x, v0.y, v0.z, v0.w, v1.x, v1.y, v1.z, v1.w};
      uint16_t hi[8], lo[8];
#pragma unroll
      for (int j = 0; j < 8; ++j) { hi[j] = f2bf(v[j]); lo[j] = f2bf(v[j] - bf2f(hi[j])); }
      int lz = b + ((k8 & 3) << 4);
      *(uint4*)&afr[k8 >> 2][0][lz][0] = *(uint4*)hi;
      *(uint4*)&afr[k8 >> 2][1][lz][0] = *(uint4*)lo;
    }
    {
      int b = tid >> 4, kq = tid & 15;
      float zarr[4] = {zv.x, zv.y, zv.z, zv.w};
      uint16_t hi[4], lo[4];
#pragma unroll
      for (int j = 0; j < 4; ++j) { hi[j] = f2bf(zarr[j]); lo[j] = f2bf(zarr[j] - bf2f(hi[j])); }
      int ks = 8 + (kq >> 3);
      int lz = b + (((kq & 7) >> 1) << 4);
      int e0 = (kq & 1) * 4;
      *(uint2*)&afr[ks][0][lz][e0] = *(uint2*)hi;
      *(uint2*)&afr[ks][1][lz][e0] = *(uint2*)lo;
    }
    // prefetch next step's z slice (hidden under MFMA)
    float4 znext = zv;
    if (t + 1 < NT) znext = *(const float4*)(zbase + (size_t)(t + 1) * NZT);
    __syncthreads();

    // ---- MFMA: ks-outer; B from regs (ks<2) or streamed from L2 (ks>=2).
    // gates: ks<8 -> r,z,hn (acc 0,1,2); ks 8,9 -> r,z,xn (acc 0,1,3).
    f32x4v accs[4][4];
#pragma unroll
    for (int q = 0; q < 4; ++q)
#pragma unroll
      for (int g = 0; g < 4; ++g) accs[q][g] = (f32x4v){0.f, 0.f, 0.f, 0.f};

#pragma unroll
    for (int ks = 0; ks < 10; ++ks) {
      bf16x8 Ah = *(const bf16x8*)&afr[ks][0][lane][0];
      bf16x8 Al = *(const bf16x8*)&afr[ks][1][lane][0];
#pragma unroll
      for (int g = 0; g < 3; ++g) {
        const int gi = (g < 2) ? g : ((ks < 8) ? 2 : 3);
        bf16x8 bh[4], bl[4];
#pragma unroll
        for (int q = 0; q < 4; ++q) {
          const int oti = g * 4 + q;
          if (ks < 2) {
            bh[q] = Brg[ks][oti][0];
            bl[q] = Brg[ks][oti][1];
          } else {
            int ot = g * 16 + w * 4 + q;
            const uint16_t* p = baseB + (size_t)ot * 10240 + ks * 1024;
            bh[q] = *(const bf16x8*)(p);
            bl[q] = *(const bf16x8*)(p + 512);
          }
        }
        // term-spaced: q varies fastest -> >=4 indep ops between same-acc uses
#pragma unroll
        for (int q = 0; q < 4; ++q) accs[q][gi] = mfma16(Ah, bh[q], accs[q][gi]);
#pragma unroll
        for (int q = 0; q < 4; ++q) accs[q][gi] = mfma16(Ah, bl[q], accs[q][gi]);
#pragma unroll
        for (int q = 0; q < 4; ++q) accs[q][gi] = mfma16(Al, bh[q], accs[q][gi]);
      }
    }

    // ---- in-register epilogue: gates -> h_new -> hbuf + h_hist
    float visit = (float)t * (1.0f / 511.0f);
#pragma unroll
    for (int q = 0; q < 4; ++q) {
      int jcol = (w * 4 + q) * 16 + l15;
#pragma unroll
      for (int r = 0; r < 4; ++r) {
        int m = l4 * 4 + r;
        float lr = accs[q][0][r] + b2r[q][r] + visit * wvr[q];
        float lz = accs[q][1][r] + b2z[q][r] + visit * wvz[q];
        float hn = accs[q][2][r] + bhn4[q];
        float xn = accs[q][3][r] + b2x[q][r] + visit * wvn[q];
        float rg = 1.0f / (1.0f + __expf(-lr));
        float zg = 1.0f / (1.0f + __expf(-lz));
        float e2 = __expf(2.0f * (xn + rg * hn));
        float ng = 1.0f - 2.0f / (e2 + 1.0f);
        float hp = hbuf[m][jcol];
        float hv = (1.0f - zg) * ng + zg * hp;
        hbuf[m][jcol] = hv;
        h_hist[((size_t)(bb * 16 + m) * NT + t) * NH + jcol] = hv;
      }
    }
    __syncthreads();
    zv = znext;
  }
}

// ---------------- fused temporal heads: temporal_cont, hazards, tcat3, mask -------
__global__ __launch_bounds__(256)
void k_heads(const float* __restrict__ h_hist, const float* __restrict__ tcw,
             const float* __restrict__ tcb, const float* __restrict__ i1w,
             const float* __restrict__ i1b, const float* __restrict__ i2w,
             const float* __restrict__ i2b, const float* __restrict__ tcatw,
             const float* __restrict__ tcatb, float* __restrict__ out,
             float* __restrict__ hazard, uint32_t g2a, uint32_t g2b) {
  int r = blockIdx.x * 256 + threadIdx.x;       // 512 blocks -> 131072 rows
  const float* hr = h_hist + (size_t)r * 256;
  float a[16] = {0.f}; float ai0 = 0.f, ai1 = 0.f; float at[5] = {0.f};
  for (int k4 = 0; k4 < 64; ++k4) {
    float4 hv = *(const float4*)(hr + k4 * 4);
#pragma unroll
    for (int i = 0; i < 16; ++i) {
      float4 wv = *(const float4*)(tcw + i * 256 + k4 * 4);
      a[i] += hv.x * wv.x + hv.y * wv.y + hv.z * wv.z + hv.w * wv.w;
    }
    { float4 wv = *(const float4*)(i1w + k4 * 4); ai0 += hv.x * wv.x + hv.y * wv.y + hv.z * wv.z + hv.w * wv.w; }
    { float4 wv = *(const float4*)(i2w + k4 * 4); ai1 += hv.x * wv.x + hv.y * wv.y + hv.z * wv.z + hv.w * wv.w; }
#pragma unroll
    for (int i = 0; i < 5; ++i) {
      float4 wv = *(const float4*)(tcatw + i * 256 + k4 * 4);
      at[i] += hv.x * wv.x + hv.y * wv.y + hv.z * wv.z + hv.w * wv.w;
    }
  }
  float* o2 = out + OUT_TC + (size_t)r * 16;
#pragma unroll
  for (int i = 0; i < 16; ++i) o2[i] = tanhf(a[i] + tcb[i]) * 0.5f + 0.5f;
  float h0 = 1.0f / (1.0f + expf(-(ai0 + i1b[0])));
  float h1 = 1.0f / (1.0f + expf(-(ai1 + i2b[0])));
  hazard[(size_t)r * 2 + 0] = h0;
  hazard[(size_t)r * 2 + 1] = h1;
  float lg[5];
#pragma unroll
  for (int i = 0; i < 5; ++i) lg[i] = at[i] + tcatb[i] + gumbel_pt(g2a, g2b, (uint32_t)(r * 5 + i));
  float m = lg[0];
#pragma unroll
  for (int i = 1; i < 5; ++i) m = fmaxf(m, lg[i]);
  float e[5], s = 0.f;
#pragma unroll
  for (int i = 0; i < 5; ++i) { e[i] = expf(lg[i] - m); s += e[i]; }
  float* o3 = out + OUT_TCAT + (size_t)r * 9;
#pragma unroll
  for (int i = 0; i < 5; ++i) o3[4 + i] = e[i] / s;
  out[OUT_MASK + r] = 1.0f;
}

// ------- irreversible states, parallel: absorbed_t = prefix-OR(hz>0.5) ----------
// s1_t>0.5 iff s1_{t-1}>0.5 or hz_t>0.5  =>  output at t is "absorbed" iff
// t > tfirst, where tfirst = 0 if init absorbed else min{t>=1: hz_t>0.5}.
__global__ void k_scan(const float* __restrict__ init, const float* __restrict__ hazard,
                       float* __restrict__ out) {
  int w = threadIdx.x >> 6, l = threadIdx.x & 63;
  int task = blockIdx.x * 4 + w;       // grid 128 x 4 waves = 512 = 256 b x 2 var
  int b = task >> 1, var = task & 1;
  float hz[8]; int tmin = 1 << 20;
#pragma unroll
  for (int c = 0; c < 8; ++c) {
    int t = 1 + c * 64 + l;
    hz[c] = 0.0f;
    if (t < NT) {
      hz[c] = hazard[((size_t)b * NT + t) * 2 + var];
      if (hz[c] > 0.5f) tmin = min(tmin, t);
    }
  }
#pragma unroll
  for (int m = 32; m > 0; m >>= 1) tmin = min(tmin, __shfl_xor(tmin, m));
  float s1i = init[b * 4 + var * 2 + 1];
  if (s1i > 0.5f) tmin = 0;
  float* tc = out + OUT_TCAT + (size_t)b * NT * 9 + var * 2;
  if (l == 0) { tc[0] = init[b * 4 + var * 2]; tc[1] = s1i; }
#pragma unroll
  for (int c = 0; c < 8; ++c) {
    int t = 1 + c * 64 + l;
    if (t < NT) {
      bool ab = t > tmin;
      float s1 = ab ? 1.0f : hz[c];
      float s0 = ab ? 0.0f : 1.0f - hz[c];
      tc[(size_t)t * 9 + 0] = s0;
      tc[(size_t)t * 9 + 1] = s1;
    }
  }
}

// =============================== launch ===============================
extern "C" void kernel_launch(void* const* d_in, const int* in_sizes, int n_in,
                              void* d_out, int out_size, void* d_ws, size_t ws_size,
                              hipStream_t stream) {
  (void)in_sizes; (void)n_in; (void)out_size; (void)ws_size;
  const float* z_static = (const float*)d_in[0];
  const float* z_temporal = (const float*)d_in[1];
  const float* initial_states = (const float*)d_in[2];
  const float* sn_w1 = (const float*)d_in[3];
  const float* sn_b1 = (const float*)d_in[4];
  const float* bn1_g = (const float*)d_in[5];
  const float* bn1_b = (const float*)d_in[6];
  const float* sn_w2 = (const float*)d_in[7];
  const float* sn_b2 = (const float*)d_in[8];
  const float* bn2_g = (const float*)d_in[9];
  const float* bn2_b = (const float*)d_in[10];
  const float* sc_w = (const float*)d_in[11];
  const float* sc_b = (const float*)d_in[12];
  const float* scat1_w = (const float*)d_in[13];
  const float* scat1_b = (const float*)d_in[14];
  const float* scat2_w = (const float*)d_in[15];
  const float* scat2_b = (const float*)d_in[16];
  const float* gru_wih = (const float*)d_in[17];
  const float* gru_whh = (const float*)d_in[18];
  const float* gru_bih = (const float*)d_in[19];
  const float* gru_bhh = (const float*)d_in[20];
  const float* tc_w = (const float*)d_in[21];
  const float* tc_b = (const float*)d_in[22];
  const float* irr1_w = (const float*)d_in[23];
  const float* irr1_b = (const float*)d_in[24];
  const float* irr2_w = (const float*)d_in[25];
  const float* irr2_b = (const float*)d_in[26];
  const float* tcat_w = (const float*)d_in[27];
  const float* tcat_b = (const float*)d_in[28];

  float* out = (float*)d_out;
  float* ws = (float*)d_ws;
  float* bl1 = ws + WS_BL1;
  float* baseline = ws + WS_BASE;
  float* bias2 = ws + WS_BIAS;
  float* h_hist = ws + WS_HHIST;
  float* hazard = ws + WS_HAZ;
  uint16_t* bfrag = (uint16_t*)(ws + WS_BFRAG);

  // JAX gk = split(key(42), 3), partitionable foldlike: gk[i] = block((0,42),(0,i))
  uint32_t gk[3][2];
  for (uint32_t i = 0; i < 3; ++i) {
    uint32_t a = 0u, b = i;
    tf2x32(0u, 42u, a, b);
    gk[i][0] = a; gk[i][1] = b;
  }

  k_prep<<<240, 256, 0, stream>>>(gru_whh, gru_wih, bfrag);
  k_static<<<256, 256, 0, stream>>>(z_static, 64, sn_w1, sn_b1, bn1_g, bn1_b, bl1);
  k_static<<<256, 256, 0, stream>>>(bl1, 256, sn_w2, sn_b2, bn2_g, bn2_b, baseline);
  k_bias<<<256, 256, 0, stream>>>(baseline, initial_states, gru_wih, gru_bih, gru_bhh, bias2);
  k_sheads<<<256, 64, 0, stream>>>(baseline, sc_w, sc_b, scat1_w, scat1_b, scat2_w, scat2_b,
                                   out, gk[0][0], gk[0][1], gk[1][0], gk[1][1]);

  k_persist<<<16, 256, 0, stream>>>(z_temporal, bfrag, bias2, gru_wih, gru_bhh, h_hist);

  k_heads<<<512, 256, 0, stream>>>(h_hist, tc_w, tc_b, irr1_w, irr1_b, irr2_w, irr2_b,
                                   tcat_w, tcat_b, out, hazard, gk[2][0], gk[2][1]);
  k_scan<<<128, 256, 0, stream>>>(initial_states, hazard, out);
}

// Round 6
// 10968.024 us; speedup vs baseline: 1.2189x; 1.2189x over previous
//
#include <hip/hip_runtime.h>
#include <stdint.h>
#include <stddef.h>

// Problem constants
#define NB 256
#define NT 512
#define NH 256
#define NZT 64
#define BN_EPS 1e-5f

// d_out offsets (floats)
#define OUT_SC    0
#define OUT_SCAT  2048
#define OUT_TC    4608
#define OUT_TCAT  2101760
#define OUT_MASK  3281408

// workspace offsets (floats)
#define WS_BL1    0
#define WS_BASE   65536
#define WS_BIAS   131072     // bias2 [256][768] (includes bhh for o<512)
#define WS_HHIST  327680     // h history [B][T][H] = 33,554,432 floats
#define WS_HAZ    33882112   // hazard [B*T][2]
#define WS_BFRAG  34144256   // B fragments (ushort), 491,520 ushorts
// total ≈ 34,390,016 floats ≈ 131.2 MiB

typedef __bf16 bf16x8 __attribute__((ext_vector_type(8)));
typedef float f32x4v __attribute__((ext_vector_type(4)));

// ---------------- threefry2x32 (JAX constants, 20 rounds) ----------------
__host__ __device__ inline void tf2x32(uint32_t k0, uint32_t k1, uint32_t& x0, uint32_t& x1) {
  uint32_t k2 = k0 ^ k1 ^ 0x1BD11BDAu;
#define RR(d) { x0 += x1; x1 = (x1 << d) | (x1 >> (32 - d)); x1 ^= x0; }
  x0 += k0; x1 += k1;
  RR(13) RR(15) RR(26) RR(6)  x0 += k1; x1 += k2 + 1u;
  RR(17) RR(29) RR(16) RR(24) x0 += k2; x1 += k0 + 2u;
  RR(13) RR(15) RR(26) RR(6)  x0 += k0; x1 += k1 + 3u;
  RR(17) RR(29) RR(16) RR(24) x0 += k1; x1 += k2 + 4u;
  RR(13) RR(15) RR(26) RR(6)  x0 += k2; x1 += k0 + 5u;
#undef RR
}

// partitionable-mode random bits for 32-bit draws: block (0, idx), bits = x0^x1
__device__ inline float gumbel_pt(uint32_t k0, uint32_t k1, uint32_t idx) {
  uint32_t x0 = 0u, x1 = idx;
  tf2x32(k0, k1, x0, x1);
  uint32_t bits = x0 ^ x1;
  uint32_t fb = (bits >> 9) | 0x3F800000u;
  float f = __uint_as_float(fb) - 1.0f;            // [0,1)
  const float TINY = 1.17549435e-38f;
  f = f * (1.0f - TINY) + TINY;                    // uniform(minval=tiny, maxval=1)
  f = fmaxf(TINY, f);
  return -logf(-logf(f));
}

// ---------------- bf16 split helpers (RNE) ----------------
__device__ inline uint16_t f2bf(float v) {
  uint32_t u = __float_as_uint(v);
  u += 0x7FFFu + ((u >> 16) & 1u);
  return (uint16_t)(u >> 16);
}
__device__ inline float bf2f(uint16_t h) { return __uint_as_float(((uint32_t)h) << 16); }

__device__ inline f32x4v mfma16(bf16x8 a, bf16x8 b, f32x4v c) {
  return __builtin_amdgcn_mfma_f32_16x16x32_bf16(a, b, c, 0, 0, 0);
}

// ---------------- prep: build B fragments (bf16 hi/lo, MFMA layout) ----
// Bfrag layout: [ot(48)][ks(10)][part(2)][lane(64)][8]  (16B per lane item)
// element: k = ks*32 + (lane>>4)*8 + j ; o = ot*16 + (lane&15)
// B[k][o] = (k<256) ? whh[o][k] : wih[o][k-256]   (z_t occupies wih cols 0..63)
__global__ void k_prep(const float* __restrict__ whh, const float* __restrict__ wih,
                       uint16_t* __restrict__ bfrag) {
  int gid = blockIdx.x * 256 + threadIdx.x;   // grid 240 x 256 = 61440
  if (gid >= 61440) return;
  int l = gid & 63;
  int rest = gid >> 6;
  int part = rest & 1; rest >>= 1;
  int ks = rest % 10, ot = rest / 10;
  uint16_t outv[8];
#pragma unroll
  for (int j = 0; j < 8; ++j) {
    int k = ks * 32 + (l >> 4) * 8 + j;
    int o = ot * 16 + (l & 15);
    float v = (k < 256) ? whh[o * 256 + k] : wih[o * 325 + (k - 256)];
    uint16_t hi = f2bf(v);
    outv[j] = (part == 0) ? hi : f2bf(v - bf2f(hi));
  }
  *(uint4*)(bfrag + (size_t)gid * 8) = *(uint4*)outv;
}

// ---------------- static layer: relu(x@W^T+b) then BatchNorm (batch stats) ----
__global__ void k_static(const float* __restrict__ x, int K, const float* __restrict__ w,
                         const float* __restrict__ bias, const float* __restrict__ g,
                         const float* __restrict__ bb, float* __restrict__ out) {
  int c = blockIdx.x, r = threadIdx.x;
  const float* wr = w + c * K;              // wave-uniform -> s_loads
  float acc = bias[c];
  for (int k = 0; k < K; ++k) acc += x[r * K + k] * wr[k];
  float v = fmaxf(acc, 0.0f);
  __shared__ float red[256];
  red[r] = v; __syncthreads();
  for (int s = 128; s > 0; s >>= 1) { if (r < s) red[r] += red[r + s]; __syncthreads(); }
  float m = red[0] * (1.0f / 256.0f);
  __syncthreads();
  float d = v - m;
  red[r] = d * d; __syncthreads();
  for (int s = 128; s > 0; s >>= 1) { if (r < s) red[r] += red[r + s]; __syncthreads(); }
  float var = red[0] * (1.0f / 256.0f);
  out[r * NH + c] = d * rsqrtf(var + BN_EPS) * g[c] + bb[c];
}

// ------- bias2[b][o] = bih[o] + baseline[b]·wih[o,64:320] + init·wih[o,321:325]
//         + (o<512 ? bhh[o] : 0)    (visit term handled per-step)
__global__ void k_bias(const float* __restrict__ baseline, const float* __restrict__ init,
                       const float* __restrict__ wih, const float* __restrict__ bih,
                       const float* __restrict__ bhh, float* __restrict__ bias2) {
  int b = blockIdx.x, tid = threadIdx.x;
  __shared__ float bl[256];
  __shared__ float in4[4];
  bl[tid] = baseline[b * 256 + tid];
  if (tid < 4) in4[tid] = init[b * 4 + tid];
  __syncthreads();
  for (int oo = 0; oo < 3; ++oo) {
    int o = oo * 256 + tid;
    const float* wr = wih + (size_t)o * 325;
    float acc = bih[o];
    for (int k = 0; k < 256; ++k) acc += bl[k] * wr[64 + k];
#pragma unroll
    for (int i = 0; i < 4; ++i) acc += in4[i] * wr[321 + i];
    if (o < 512) acc += bhh[o];
    bias2[b * 768 + o] = acc;
  }
}

// ---------------- static heads: static_cont + gumbel-softmax static_cat ----------
__global__ void k_sheads(const float* __restrict__ baseline, const float* __restrict__ sc_w,
                         const float* __restrict__ sc_b, const float* __restrict__ s1w,
                         const float* __restrict__ s1b, const float* __restrict__ s2w,
                         const float* __restrict__ s2b, float* __restrict__ out,
                         uint32_t g0a, uint32_t g0b, uint32_t g1a, uint32_t g1b) {
  int b = blockIdx.x, tid = threadIdx.x;   // 64 threads
  __shared__ float bl[256];
  __shared__ float lg[10];
  for (int i = tid; i < 256; i += 64) bl[i] = baseline[b * 256 + i];
  __syncthreads();
  if (tid < 18) {
    const float* wr; float bias;
    if (tid < 8)       { wr = sc_w + tid * 256;        bias = sc_b[tid]; }
    else if (tid < 12) { wr = s1w + (tid - 8) * 256;   bias = s1b[tid - 8]; }
    else               { wr = s2w + (tid - 12) * 256;  bias = s2b[tid - 12]; }
    float acc = bias;
    for (int k = 0; k < 256; ++k) acc += bl[k] * wr[k];
    if (tid < 8)       out[OUT_SC + b * 8 + tid] = tanhf(acc) * 0.5f + 0.5f;
    else if (tid < 12) lg[tid - 8] = acc + gumbel_pt(g0a, g0b, (uint32_t)(b * 4 + (tid - 8)));
    else               lg[tid - 8] = acc + gumbel_pt(g1a, g1b, (uint32_t)(b * 6 + (tid - 12)));
  }
  __syncthreads();
  if (tid == 0) {
    float m = fmaxf(fmaxf(lg[0], lg[1]), fmaxf(lg[2], lg[3]));
    float e[4], s = 0.f;
    for (int i = 0; i < 4; ++i) { e[i] = expf(lg[i] - m); s += e[i]; }
    float* o1 = out + OUT_SCAT + b * 10;
    for (int i = 0; i < 4; ++i) o1[i] = e[i] / s;
  } else if (tid == 1) {
    float m = lg[4];
    for (int i = 5; i < 10; ++i) m = fmaxf(m, lg[i]);
    float e[6], s = 0.f;
    for (int i = 0; i < 6; ++i) { e[i] = expf(lg[4 + i] - m); s += e[i]; }
    float* o1 = out + OUT_SCAT + b * 10 + 4;
    for (int i = 0; i < 6; ++i) o1[i] = e[i] / s;
  }
}

// ---------------- persistent GRU: 16 blocks x 512 threads (8 waves, 2/SIMD) ------
// Block bb owns batch rows [bb*16, bb*16+16). Wave w owns q-tiles {2w, 2w+1}
// (h cols [q*16, q*16+16)) and their r/z/n gate tiles (ot = g*16 + q).
// B streamed from L2 with a 3-deep (ks,g)-stage software pipeline (4-slot ring).
// bf16x3 split MFMA throughout. No register-pinned B (round-3 spill lesson).
__global__ __launch_bounds__(512, 2)
void k_persist(const float* __restrict__ zt, const uint16_t* __restrict__ bfrag,
               const float* __restrict__ bias2, const float* __restrict__ wih,
               const float* __restrict__ bhh, float* __restrict__ h_hist) {
  int bb = blockIdx.x;
  int tid = threadIdx.x;
  int w = tid >> 6, lane = tid & 63;
  int l15 = lane & 15, l4 = lane >> 4;
  int q0 = w * 2;

  __shared__ __align__(16) uint16_t afr[10][2][64][8];   // A fragments hi/lo (20 KB)
  __shared__ __align__(16) float hbuf[16][260];          // h state f32 (16.6 KB)

  // zero h0
  for (int i = tid; i < 16 * 260; i += 512) ((float*)hbuf)[i] = 0.0f;

  // per-lane epilogue constants (2 q-tiles): 32 VGPRs
  float b2r[2][4], b2z[2][4], b2x[2][4], bhn2[2], wvr[2], wvz[2], wvn[2];
#pragma unroll
  for (int qq = 0; qq < 2; ++qq) {
    int j = (q0 + qq) * 16 + l15;
    wvr[qq] = wih[(size_t)j * 325 + 320];
    wvz[qq] = wih[(size_t)(256 + j) * 325 + 320];
    wvn[qq] = wih[(size_t)(512 + j) * 325 + 320];
    bhn2[qq] = bhh[512 + j];
#pragma unroll
    for (int r = 0; r < 4; ++r) {
      int brow = bb * 16 + l4 * 4 + r;
      b2r[qq][r] = bias2[brow * 768 + j];
      b2z[qq][r] = bias2[brow * 768 + 256 + j];
      b2x[qq][r] = bias2[brow * 768 + 512 + j];
    }
  }

  // z prefetch: threads 0..255 own z[b = tid>>4][ (tid&15)*4 .. +4 ] per t
  const float* zbase = zt + (size_t)(bb * 16 + ((tid & 255) >> 4)) * NT * NZT + (tid & 15) * 4;
  float4 zv = {0.f, 0.f, 0.f, 0.f};
  if (tid < 256) zv = *(const float4*)zbase;

  const uint16_t* baseB = bfrag + (size_t)lane * 8;
#define BADDR(ks, g, qq, part) ((const bf16x8*)(baseB + \
    ((size_t)((g) * 16 + q0 + (qq)) * 10240 + (ks) * 1024 + (part) * 512)))

  __syncthreads();

#pragma unroll 1
  for (int t = 0; t < NT; ++t) {
    // ---- stage A fragments: h (ks 0..7) from hbuf (1 item/thread), z (ks 8,9)
    {
      int b = tid >> 5, k8 = tid & 31;
      float4 v0 = *(const float4*)&hbuf[b][k8 * 8];
      float4 v1 = *(const float4*)&hbuf[b][k8 * 8 + 4];
      float v[8] = {v0.x, v0.y, v0.z, v0.w, v1.x, v1.y, v1.z, v1.w};
      uint16_t hi[8], lo[8];
#pragma unroll
      for (int j = 0; j < 8; ++j) { hi[j] = f2bf(v[j]); lo[j] = f2bf(v[j] - bf2f(hi[j])); }
      int lz = b + ((k8 & 3) << 4);
      *(uint4*)&afr[k8 >> 2][0][lz][0] = *(uint4*)hi;
      *(uint4*)&afr[k8 >> 2][1][lz][0] = *(uint4*)lo;
    }
    if (tid < 256) {
      int b = tid >> 4, kq = tid & 15;
      float zarr[4] = {zv.x, zv.y, zv.z, zv.w};
      uint16_t hi[4], lo[4];
#pragma unroll
      for (int j = 0; j < 4; ++j) { hi[j] = f2bf(zarr[j]); lo[j] = f2bf(zarr[j] - bf2f(hi[j])); }
      int ks = 8 + (kq >> 3);
      int lz = b + (((kq & 7) >> 1) << 4);
      int e0 = (kq & 1) * 4;
      *(uint2*)&afr[ks][0][lz][e0] = *(uint2*)hi;
      *(uint2*)&afr[ks][1][lz][e0] = *(uint2*)lo;
    }
    // prefetch next step's z slice (hidden under MFMA)
    float4 znext = zv;
    if (tid < 256 && t + 1 < NT) znext = *(const float4*)(zbase + (size_t)(t + 1) * NZT);
    __syncthreads();

    // ---- MFMA: 30 stages (ks 0..9 x g 0..2), 3-deep B pipeline, 4-slot ring
    f32x4v accs[2][4];
#pragma unroll
    for (int qq = 0; qq < 2; ++qq)
#pragma unroll
      for (int g = 0; g < 4; ++g) accs[qq][g] = (f32x4v){0.f, 0.f, 0.f, 0.f};

    bf16x8 A2h[2], A2l[2];
    A2h[0] = *(const bf16x8*)&afr[0][0][lane][0];
    A2l[0] = *(const bf16x8*)&afr[0][1][lane][0];

    bf16x8 bq[4][4];
#pragma unroll
    for (int s = 0; s < 3; ++s) {
      bq[s][0] = *BADDR(0, s, 0, 0);
      bq[s][1] = *BADDR(0, s, 0, 1);
      bq[s][2] = *BADDR(0, s, 1, 0);
      bq[s][3] = *BADDR(0, s, 1, 1);
    }

#pragma unroll
    for (int s = 0; s < 30; ++s) {
      const int ks = s / 3, g = s % 3;
      const int gi = (g < 2) ? g : ((ks < 8) ? 2 : 3);
      // A prefetch one ks ahead (at g==0)
      if (g == 0 && ks < 9) {
        A2h[(ks + 1) & 1] = *(const bf16x8*)&afr[ks + 1][0][lane][0];
        A2l[(ks + 1) & 1] = *(const bf16x8*)&afr[ks + 1][1][lane][0];
      }
      // B prefetch 3 stages ahead into ring slot (s+3)&3 (!= s&3)
      if (s + 3 < 30) {
        const int ks2 = (s + 3) / 3, g2 = (s + 3) % 3, sl = (s + 3) & 3;
        bq[sl][0] = *BADDR(ks2, g2, 0, 0);
        bq[sl][1] = *BADDR(ks2, g2, 0, 1);
        bq[sl][2] = *BADDR(ks2, g2, 1, 0);
        bq[sl][3] = *BADDR(ks2, g2, 1, 1);
      }
      bf16x8 Ah = A2h[ks & 1], Al = A2l[ks & 1];
      const int sl0 = s & 3;
      // 6 MFMAs, q alternating -> >=2 indep ops between same-acc uses
      accs[0][gi] = mfma16(Ah, bq[sl0][0], accs[0][gi]);
      accs[1][gi] = mfma16(Ah, bq[sl0][2], accs[1][gi]);
      accs[0][gi] = mfma16(Ah, bq[sl0][1], accs[0][gi]);
      accs[1][gi] = mfma16(Ah, bq[sl0][3], accs[1][gi]);
      accs[0][gi] = mfma16(Al, bq[sl0][0], accs[0][gi]);
      accs[1][gi] = mfma16(Al, bq[sl0][2], accs[1][gi]);
    }

    // ---- in-register epilogue: gates -> h_new -> hbuf + h_hist
    float visit = (float)t * (1.0f / 511.0f);
#pragma unroll
    for (int qq = 0; qq < 2; ++qq) {
      int jcol = (q0 + qq) * 16 + l15;
#pragma unroll
      for (int r = 0; r < 4; ++r) {
        int m = l4 * 4 + r;
        float lr = accs[qq][0][r] + b2r[qq][r] + visit * wvr[qq];
        float lz = accs[qq][1][r] + b2z[qq][r] + visit * wvz[qq];
        float hn = accs[qq][2][r] + bhn2[qq];
        float xn = accs[qq][3][r] + b2x[qq][r] + visit * wvn[qq];
        float rg = 1.0f / (1.0f + __expf(-lr));
        float zg = 1.0f / (1.0f + __expf(-lz));
        float e2 = __expf(2.0f * (xn + rg * hn));
        float ng = 1.0f - 2.0f / (e2 + 1.0f);
        float hp = hbuf[m][jcol];
        float hv = (1.0f - zg) * ng + zg * hp;
        hbuf[m][jcol] = hv;
        h_hist[((size_t)(bb * 16 + m) * NT + t) * NH + jcol] = hv;
      }
    }
    __syncthreads();
    zv = znext;
  }
#undef BADDR
}

// ---------------- fused temporal heads: temporal_cont, hazards, tcat3, mask -------
__global__ __launch_bounds__(256)
void k_heads(const float* __restrict__ h_hist, const float* __restrict__ tcw,
             const float* __restrict__ tcb, const float* __restrict__ i1w,
             const float* __restrict__ i1b, const float* __restrict__ i2w,
             const float* __restrict__ i2b, const float* __restrict__ tcatw,
             const float* __restrict__ tcatb, float* __restrict__ out,
             float* __restrict__ hazard, uint32_t g2a, uint32_t g2b) {
  int r = blockIdx.x * 256 + threadIdx.x;       // 512 blocks -> 131072 rows
  const float* hr = h_hist + (size_t)r * 256;
  float a[16] = {0.f}; float ai0 = 0.f, ai1 = 0.f; float at[5] = {0.f};
  for (int k4 = 0; k4 < 64; ++k4) {
    float4 hv = *(const float4*)(hr + k4 * 4);
#pragma unroll
    for (int i = 0; i < 16; ++i) {
      float4 wv = *(const float4*)(tcw + i * 256 + k4 * 4);
      a[i] += hv.x * wv.x + hv.y * wv.y + hv.z * wv.z + hv.w * wv.w;
    }
    { float4 wv = *(const float4*)(i1w + k4 * 4); ai0 += hv.x * wv.x + hv.y * wv.y + hv.z * wv.z + hv.w * wv.w; }
    { float4 wv = *(const float4*)(i2w + k4 * 4); ai1 += hv.x * wv.x + hv.y * wv.y + hv.z * wv.z + hv.w * wv.w; }
#pragma unroll
    for (int i = 0; i < 5; ++i) {
      float4 wv = *(const float4*)(tcatw + i * 256 + k4 * 4);
      at[i] += hv.x * wv.x + hv.y * wv.y + hv.z * wv.z + hv.w * wv.w;
    }
  }
  float* o2 = out + OUT_TC + (size_t)r * 16;
#pragma unroll
  for (int i = 0; i < 16; ++i) o2[i] = tanhf(a[i] + tcb[i]) * 0.5f + 0.5f;
  float h0 = 1.0f / (1.0f + expf(-(ai0 + i1b[0])));
  float h1 = 1.0f / (1.0f + expf(-(ai1 + i2b[0])));
  hazard[(size_t)r * 2 + 0] = h0;
  hazard[(size_t)r * 2 + 1] = h1;
  float lg[5];
#pragma unroll
  for (int i = 0; i < 5; ++i) lg[i] = at[i] + tcatb[i] + gumbel_pt(g2a, g2b, (uint32_t)(r * 5 + i));
  float m = lg[0];
#pragma unroll
  for (int i = 1; i < 5; ++i) m = fmaxf(m, lg[i]);
  float e[5], s = 0.f;
#pragma unroll
  for (int i = 0; i < 5; ++i) { e[i] = expf(lg[i] - m); s += e[i]; }
  float* o3 = out + OUT_TCAT + (size_t)r * 9;
#pragma unroll
  for (int i = 0; i < 5; ++i) o3[4 + i] = e[i] / s;
  out[OUT_MASK + r] = 1.0f;
}

// ------- irreversible states, parallel: absorbed_t = prefix-OR(hz>0.5) ----------
// s1_t>0.5 iff s1_{t-1}>0.5 or hz_t>0.5  =>  output at t is "absorbed" iff
// t > tfirst, where tfirst = 0 if init absorbed else min{t>=1: hz_t>0.5}.
__global__ void k_scan(const float* __restrict__ init, const float* __restrict__ hazard,
                       float* __restrict__ out) {
  int w = threadIdx.x >> 6, l = threadIdx.x & 63;
  int task = blockIdx.x * 4 + w;       // grid 128 x 4 waves = 512 = 256 b x 2 var
  int b = task >> 1, var = task & 1;
  float hz[8]; int tmin = 1 << 20;
#pragma unroll
  for (int c = 0; c < 8; ++c) {
    int t = 1 + c * 64 + l;
    hz[c] = 0.0f;
    if (t < NT) {
      hz[c] = hazard[((size_t)b * NT + t) * 2 + var];
      if (hz[c] > 0.5f) tmin = min(tmin, t);
    }
  }
#pragma unroll
  for (int m = 32; m > 0; m >>= 1) tmin = min(tmin, __shfl_xor(tmin, m));
  float s1i = init[b * 4 + var * 2 + 1];
  if (s1i > 0.5f) tmin = 0;
  float* tc = out + OUT_TCAT + (size_t)b * NT * 9 + var * 2;
  if (l == 0) { tc[0] = init[b * 4 + var * 2]; tc[1] = s1i; }
#pragma unroll
  for (int c = 0; c < 8; ++c) {
    int t = 1 + c * 64 + l;
    if (t < NT) {
      bool ab = t > tmin;
      float s1 = ab ? 1.0f : hz[c];
      float s0 = ab ? 0.0f : 1.0f - hz[c];
      tc[(size_t)t * 9 + 0] = s0;
      tc[(size_t)t * 9 + 1] = s1;
    }
  }
}

// =============================== launch ===============================
extern "C" void kernel_launch(void* const* d_in, const int* in_sizes, int n_in,
                              void* d_out, int out_size, void* d_ws, size_t ws_size,
                              hipStream_t stream) {
  (void)in_sizes; (void)n_in; (void)out_size; (void)ws_size;
  const float* z_static = (const float*)d_in[0];
  const float* z_temporal = (const float*)d_in[1];
  const float* initial_states = (const float*)d_in[2];
  const float* sn_w1 = (const float*)d_in[3];
  const float* sn_b1 = (const float*)d_in[4];
  const float* bn1_g = (const float*)d_in[5];
  const float* bn1_b = (const float*)d_in[6];
  const float* sn_w2 = (const float*)d_in[7];
  const float* sn_b2 = (const float*)d_in[8];
  const float* bn2_g = (const float*)d_in[9];
  const float* bn2_b = (const float*)d_in[10];
  const float* sc_w = (const float*)d_in[11];
  const float* sc_b = (const float*)d_in[12];
  const float* scat1_w = (const float*)d_in[13];
  const float* scat1_b = (const float*)d_in[14];
  const float* scat2_w = (const float*)d_in[15];
  const float* scat2_b = (const float*)d_in[16];
  const float* gru_wih = (const float*)d_in[17];
  const float* gru_whh = (const float*)d_in[18];
  const float* gru_bih = (const float*)d_in[19];
  const float* gru_bhh = (const float*)d_in[20];
  const float* tc_w = (const float*)d_in[21];
  const float* tc_b = (const float*)d_in[22];
  const float* irr1_w = (const float*)d_in[23];
  const float* irr1_b = (const float*)d_in[24];
  const float* irr2_w = (const float*)d_in[25];
  const float* irr2_b = (const float*)d_in[26];
  const float* tcat_w = (const float*)d_in[27];
  const float* tcat_b = (const float*)d_in[28];

  float* out = (float*)d_out;
  float* ws = (float*)d_ws;
  float* bl1 = ws + WS_BL1;
  float* baseline = ws + WS_BASE;
  float* bias2 = ws + WS_BIAS;
  float* h_hist = ws + WS_HHIST;
  float* hazard = ws + WS_HAZ;
  uint16_t* bfrag = (uint16_t*)(ws + WS_BFRAG);

  // JAX gk = split(key(42), 3), partitionable foldlike: gk[i] = block((0,42),(0,i))
  uint32_t gk[3][2];
  for (uint32_t i = 0; i < 3; ++i) {
    uint32_t a = 0u, b = i;
    tf2x32(0u, 42u, a, b);
    gk[i][0] = a; gk[i][1] = b;
  }

  k_prep<<<240, 256, 0, stream>>>(gru_whh, gru_wih, bfrag);
  k_static<<<256, 256, 0, stream>>>(z_static, 64, sn_w1, sn_b1, bn1_g, bn1_b, bl1);
  k_static<<<256, 256, 0, stream>>>(bl1, 256, sn_w2, sn_b2, bn2_g, bn2_b, baseline);
  k_bias<<<256, 256, 0, stream>>>(baseline, initial_states, gru_wih, gru_bih, gru_bhh, bias2);
  k_sheads<<<256, 64, 0, stream>>>(baseline, sc_w, sc_b, scat1_w, scat1_b, scat2_w, scat2_b,
                                   out, gk[0][0], gk[0][1], gk[1][0], gk[1][1]);

  k_persist<<<16, 512, 0, stream>>>(z_temporal, bfrag, bias2, gru_wih, gru_bhh, h_hist);

  k_heads<<<512, 256, 0, stream>>>(h_hist, tc_w, tc_b, irr1_w, irr1_b, irr2_w, irr2_b,
                                   tcat_w, tcat_b, out, hazard, gk[2][0], gk[2][1]);
  k_scan<<<128, 256, 0, stream>>>(initial_states, hazard, out);
}

// Round 10
// 10698.634 us; speedup vs baseline: 1.2496x; 1.0252x over previous
//
#include <hip/hip_runtime.h>
#include <stdint.h>
#include <stddef.h>

// Problem constants
#define NB 256
#define NT 512
#define NH 256
#define NZT 64
#define BN_EPS 1e-5f

// d_out offsets (floats)
#define OUT_SC    0
#define OUT_SCAT  2048
#define OUT_TC    4608
#define OUT_TCAT  2101760
#define OUT_MASK  3281408

// workspace offsets (floats)
#define WS_BL1    0
#define WS_BASE   65536
#define WS_BIAS   131072     // bias2 [256][768] (includes bhh for o<512)
#define WS_HHIST  327680     // h history [B][T][H] = 33,554,432 floats
#define WS_HAZ    33882112   // hazard [B*T][2]
#define WS_BFRAG  34144256   // B fragments (ushort), 491,520 ushorts
// total ≈ 34,390,016 floats ≈ 131.2 MiB

typedef __bf16 bf16x8 __attribute__((ext_vector_type(8)));
typedef float f32x4v __attribute__((ext_vector_type(4)));

// ---------------- threefry2x32 (JAX constants, 20 rounds) ----------------
__host__ __device__ inline void tf2x32(uint32_t k0, uint32_t k1, uint32_t& x0, uint32_t& x1) {
  uint32_t k2 = k0 ^ k1 ^ 0x1BD11BDAu;
#define RR(d) { x0 += x1; x1 = (x1 << d) | (x1 >> (32 - d)); x1 ^= x0; }
  x0 += k0; x1 += k1;
  RR(13) RR(15) RR(26) RR(6)  x0 += k1; x1 += k2 + 1u;
  RR(17) RR(29) RR(16) RR(24) x0 += k2; x1 += k0 + 2u;
  RR(13) RR(15) RR(26) RR(6)  x0 += k0; x1 += k1 + 3u;
  RR(17) RR(29) RR(16) RR(24) x0 += k1; x1 += k2 + 4u;
  RR(13) RR(15) RR(26) RR(6)  x0 += k2; x1 += k0 + 5u;
#undef RR
}

// partitionable-mode random bits for 32-bit draws: block (0, idx), bits = x0^x1
__device__ inline float gumbel_pt(uint32_t k0, uint32_t k1, uint32_t idx) {
  uint32_t x0 = 0u, x1 = idx;
  tf2x32(k0, k1, x0, x1);
  uint32_t bits = x0 ^ x1;
  uint32_t fb = (bits >> 9) | 0x3F800000u;
  float f = __uint_as_float(fb) - 1.0f;            // [0,1)
  const float TINY = 1.17549435e-38f;
  f = f * (1.0f - TINY) + TINY;                    // uniform(minval=tiny, maxval=1)
  f = fmaxf(TINY, f);
  return -logf(-logf(f));
}

// ---------------- bf16 split helpers (RNE) ----------------
__device__ inline uint16_t f2bf(float v) {
  uint32_t u = __float_as_uint(v);
  u += 0x7FFFu + ((u >> 16) & 1u);
  return (uint16_t)(u >> 16);
}
__device__ inline float bf2f(uint16_t h) { return __uint_as_float(((uint32_t)h) << 16); }

__device__ inline f32x4v mfma16(bf16x8 a, bf16x8 b, f32x4v c) {
  return __builtin_amdgcn_mfma_f32_16x16x32_bf16(a, b, c, 0, 0, 0);
}

// ---------------- prep: build B fragments (bf16 hi/lo, MFMA layout) ----
// Bfrag layout: [ot(48)][ks(10)][part(2)][lane(64)][8]  (16B per lane item)
// element: k = ks*32 + (lane>>4)*8 + j ; o = ot*16 + (lane&15)
// B[k][o] = (k<256) ? whh[o][k] : wih[o][k-256]   (z_t occupies wih cols 0..63)
__global__ void k_prep(const float* __restrict__ whh, const float* __restrict__ wih,
                       uint16_t* __restrict__ bfrag) {
  int gid = blockIdx.x * 256 + threadIdx.x;   // grid 240 x 256 = 61440
  if (gid >= 61440) return;
  int l = gid & 63;
  int rest = gid >> 6;
  int part = rest & 1; rest >>= 1;
  int ks = rest % 10, ot = rest / 10;
  uint16_t outv[8];
#pragma unroll
  for (int j = 0; j < 8; ++j) {
    int k = ks * 32 + (l >> 4) * 8 + j;
    int o = ot * 16 + (l & 15);
    float v = (k < 256) ? whh[o * 256 + k] : wih[o * 325 + (k - 256)];
    uint16_t hi = f2bf(v);
    outv[j] = (part == 0) ? hi : f2bf(v - bf2f(hi));
  }
  *(uint4*)(bfrag + (size_t)gid * 8) = *(uint4*)outv;
}

// ---------------- static layer: relu(x@W^T+b) then BatchNorm (batch stats) ----
__global__ void k_static(const float* __restrict__ x, int K, const float* __restrict__ w,
                         const float* __restrict__ bias, const float* __restrict__ g,
                         const float* __restrict__ bb, float* __restrict__ out) {
  int c = blockIdx.x, r = threadIdx.x;
  const float* wr = w + c * K;              // wave-uniform -> s_loads
  float acc = bias[c];
  for (int k = 0; k < K; ++k) acc += x[r * K + k] * wr[k];
  float v = fmaxf(acc, 0.0f);
  __shared__ float red[256];
  red[r] = v; __syncthreads();
  for (int s = 128; s > 0; s >>= 1) { if (r < s) red[r] += red[r + s]; __syncthreads(); }
  float m = red[0] * (1.0f / 256.0f);
  __syncthreads();
  float d = v - m;
  red[r] = d * d; __syncthreads();
  for (int s = 128; s > 0; s >>= 1) { if (r < s) red[r] += red[r + s]; __syncthreads(); }
  float var = red[0] * (1.0f / 256.0f);
  out[r * NH + c] = d * rsqrtf(var + BN_EPS) * g[c] + bb[c];
}

// ------- bias2[b][o] = bih[o] + baseline[b]·wih[o,64:320] + init·wih[o,321:325]
//         + (o<512 ? bhh[o] : 0)    (visit term handled per-step)
__global__ void k_bias(const float* __restrict__ baseline, const float* __restrict__ init,
                       const float* __restrict__ wih, const float* __restrict__ bih,
                       const float* __restrict__ bhh, float* __restrict__ bias2) {
  int b = blockIdx.x, tid = threadIdx.x;
  __shared__ float bl[256];
  __shared__ float in4[4];
  bl[tid] = baseline[b * 256 + tid];
  if (tid < 4) in4[tid] = init[b * 4 + tid];
  __syncthreads();
  for (int oo = 0; oo < 3; ++oo) {
    int o = oo * 256 + tid;
    const float* wr = wih + (size_t)o * 325;
    float acc = bih[o];
    for (int k = 0; k < 256; ++k) acc += bl[k] * wr[64 + k];
#pragma unroll
    for (int i = 0; i < 4; ++i) acc += in4[i] * wr[321 + i];
    if (o < 512) acc += bhh[o];
    bias2[b * 768 + o] = acc;
  }
}

// ---------------- static heads: static_cont + gumbel-softmax static_cat ----------
__global__ void k_sheads(const float* __restrict__ baseline, const float* __restrict__ sc_w,
                         const float* __restrict__ sc_b, const float* __restrict__ s1w,
                         const float* __restrict__ s1b, const float* __restrict__ s2w,
                         const float* __restrict__ s2b, float* __restrict__ out,
                         uint32_t g0a, uint32_t g0b, uint32_t g1a, uint32_t g1b) {
  int b = blockIdx.x, tid = threadIdx.x;   // 64 threads
  __shared__ float bl[256];
  __shared__ float lg[10];
  for (int i = tid; i < 256; i += 64) bl[i] = baseline[b * 256 + i];
  __syncthreads();
  if (tid < 18) {
    const float* wr; float bias;
    if (tid < 8)       { wr = sc_w + tid * 256;        bias = sc_b[tid]; }
    else if (tid < 12) { wr = s1w + (tid - 8) * 256;   bias = s1b[tid - 8]; }
    else               { wr = s2w + (tid - 12) * 256;  bias = s2b[tid - 12]; }
    float acc = bias;
    for (int k = 0; k < 256; ++k) acc += bl[k] * wr[k];
    if (tid < 8)       out[OUT_SC + b * 8 + tid] = tanhf(acc) * 0.5f + 0.5f;
    else if (tid < 12) lg[tid - 8] = acc + gumbel_pt(g0a, g0b, (uint32_t)(b * 4 + (tid - 8)));
    else               lg[tid - 8] = acc + gumbel_pt(g1a, g1b, (uint32_t)(b * 6 + (tid - 12)));
  }
  __syncthreads();
  if (tid == 0) {
    float m = fmaxf(fmaxf(lg[0], lg[1]), fmaxf(lg[2], lg[3]));
    float e[4], s = 0.f;
    for (int i = 0; i < 4; ++i) { e[i] = expf(lg[i] - m); s += e[i]; }
    float* o1 = out + OUT_SCAT + b * 10;
    for (int i = 0; i < 4; ++i) o1[i] = e[i] / s;
  } else if (tid == 1) {
    float m = lg[4];
    for (int i = 5; i < 10; ++i) m = fmaxf(m, lg[i]);
    float e[6], s = 0.f;
    for (int i = 0; i < 6; ++i) { e[i] = expf(lg[4 + i] - m); s += e[i]; }
    float* o1 = out + OUT_SCAT + b * 10 + 4;
    for (int i = 0; i < 6; ++i) o1[i] = e[i] / s;
  }
}

// ---------------- persistent GRU: 16 blocks x 512 threads (8 waves, 2/SIMD) ------
// Block bb owns batch rows [bb*16, bb*16+16). Wave w owns q-tiles {2w, 2w+1}
// (h cols [q*16, q*16+16)) and their r/z/n gate tiles (ot = g*16 + q).
// B streamed from L2: 6-slot ring, prefetch 5 (ks,g)-stages ahead; ring prologue
// issued BEFORE the staging barrier so its latency hides under LDS staging.
// amdgpu_waves_per_eu(2,2) pins occupancy target -> allocator gets 256 VGPRs
// (round-6 lesson: launch_bounds min alone let it squeeze to 128 and collapse
// the pipeline). bf16x3 split MFMA throughout.
__attribute__((amdgpu_waves_per_eu(2, 2)))
__global__ __launch_bounds__(512, 2)
void k_persist(const float* __restrict__ zt, const uint16_t* __restrict__ bfrag,
               const float* __restrict__ bias2, const float* __restrict__ wih,
               const float* __restrict__ bhh, float* __restrict__ h_hist) {
  int bb = blockIdx.x;
  int tid = threadIdx.x;
  int w = tid >> 6, lane = tid & 63;
  int l15 = lane & 15, l4 = lane >> 4;
  int q0 = w * 2;

  __shared__ __align__(16) uint16_t afr[10][2][64][8];   // A fragments hi/lo (20 KB)
  __shared__ __align__(16) float hbuf[16][260];          // h state f32 (16.6 KB)

  // zero h0
  for (int i = tid; i < 16 * 260; i += 512) ((float*)hbuf)[i] = 0.0f;

  // per-lane epilogue constants (2 q-tiles): 32 VGPRs
  float b2r[2][4], b2z[2][4], b2x[2][4], bhn2[2], wvr[2], wvz[2], wvn[2];
#pragma unroll
  for (int qq = 0; qq < 2; ++qq) {
    int j = (q0 + qq) * 16 + l15;
    wvr[qq] = wih[(size_t)j * 325 + 320];
    wvz[qq] = wih[(size_t)(256 + j) * 325 + 320];
    wvn[qq] = wih[(size_t)(512 + j) * 325 + 320];
    bhn2[qq] = bhh[512 + j];
#pragma unroll
    for (int r = 0; r < 4; ++r) {
      int brow = bb * 16 + l4 * 4 + r;
      b2r[qq][r] = bias2[brow * 768 + j];
      b2z[qq][r] = bias2[brow * 768 + 256 + j];
      b2x[qq][r] = bias2[brow * 768 + 512 + j];
    }
  }

  // z prefetch: threads 0..255 own z[b = tid>>4][ (tid&15)*4 .. +4 ] per t
  const float* zbase = zt + (size_t)(bb * 16 + ((tid & 255) >> 4)) * NT * NZT + (tid & 15) * 4;
  float4 zv = {0.f, 0.f, 0.f, 0.f};
  if (tid < 256) zv = *(const float4*)zbase;

  const uint16_t* baseB = bfrag + (size_t)lane * 8;
#define BADDR(ks, g, qq, part) ((const bf16x8*)(baseB + \
    ((size_t)((g) * 16 + q0 + (qq)) * 10240 + (ks) * 1024 + (part) * 512)))

  __syncthreads();

#pragma unroll 1
  for (int t = 0; t < NT; ++t) {
    // ---- B-ring prologue: stages 0..4 issued BEFORE the staging barrier,
    //      so their L2 latency hides under LDS staging + __syncthreads.
    bf16x8 bq[6][4];
#pragma unroll
    for (int s = 0; s < 5; ++s) {
      const int ks = s / 3, g = s % 3;
      bq[s][0] = *BADDR(ks, g, 0, 0);
      bq[s][1] = *BADDR(ks, g, 0, 1);
      bq[s][2] = *BADDR(ks, g, 1, 0);
      bq[s][3] = *BADDR(ks, g, 1, 1);
    }

    // ---- stage A fragments: h (ks 0..7) from hbuf (1 item/thread), z (ks 8,9)
    {
      int b = tid >> 5, k8 = tid & 31;
      float4 v0 = *(const float4*)&hbuf[b][k8 * 8];
      float4 v1 = *(const float4*)&hbuf[b][k8 * 8 + 4];
      float v[8] = {v0.x, v0.y, v0.z, v0.w, v1.x, v1.y, v1.z, v1.w};
      uint16_t hi[8], lo[8];
#pragma unroll
      for (int j = 0; j < 8; ++j) { hi[j] = f2bf(v[j]); lo[j] = f2bf(v[j] - bf2f(hi[j])); }
      int lz = b + ((k8 & 3) << 4);
      *(uint4*)&afr[k8 >> 2][0][lz][0] = *(uint4*)hi;
      *(uint4*)&afr[k8 >> 2][1][lz][0] = *(uint4*)lo;
    }
    if (tid < 256) {
      int b = tid >> 4, kq = tid & 15;
      float zarr[4] = {zv.x, zv.y, zv.z, zv.w};
      uint16_t hi[4], lo[4];
#pragma unroll
      for (int j = 0; j < 4; ++j) { hi[j] = f2bf(zarr[j]); lo[j] = f2bf(zarr[j] - bf2f(hi[j])); }
      int ks = 8 + (kq >> 3);
      int lz = b + (((kq & 7) >> 1) << 4);
      int e0 = (kq & 1) * 4;
      *(uint2*)&afr[ks][0][lz][e0] = *(uint2*)hi;
      *(uint2*)&afr[ks][1][lz][e0] = *(uint2*)lo;
    }
    // prefetch next step's z slice (hidden under MFMA)
    float4 znext = zv;
    if (tid < 256 && t + 1 < NT) znext = *(const float4*)(zbase + (size_t)(t + 1) * NZT);
    __syncthreads();

    // ---- MFMA: 30 stages (ks 0..9 x g 0..2), 5-deep B pipeline, 6-slot ring
    f32x4v accs[2][4];
#pragma unroll
    for (int qq = 0; qq < 2; ++qq)
#pragma unroll
      for (int g = 0; g < 4; ++g) accs[qq][g] = (f32x4v){0.f, 0.f, 0.f, 0.f};

    bf16x8 A2h[2], A2l[2];
    A2h[0] = *(const bf16x8*)&afr[0][0][lane][0];
    A2l[0] = *(const bf16x8*)&afr[0][1][lane][0];

#pragma unroll
    for (int s = 0; s < 30; ++s) {
      const int ks = s / 3, g = s % 3;
      const int gi = (g < 2) ? g : ((ks < 8) ? 2 : 3);
      // A prefetch one ks ahead (at g==0)
      if (g == 0 && ks < 9) {
        A2h[(ks + 1) & 1] = *(const bf16x8*)&afr[ks + 1][0][lane][0];
        A2l[(ks + 1) & 1] = *(const bf16x8*)&afr[ks + 1][1][lane][0];
      }
      // B prefetch 5 stages ahead into ring slot (s+5)%6
      if (s + 5 < 30) {
        const int s2 = s + 5;
        const int ks2 = s2 / 3, g2 = s2 % 3, sl = s2 % 6;
        bq[sl][0] = *BADDR(ks2, g2, 0, 0);
        bq[sl][1] = *BADDR(ks2, g2, 0, 1);
        bq[sl][2] = *BADDR(ks2, g2, 1, 0);
        bq[sl][3] = *BADDR(ks2, g2, 1, 1);
      }
      bf16x8 Ah = A2h[ks & 1], Al = A2l[ks & 1];
      const int sl0 = s % 6;
      // 6 MFMAs, q alternating -> indep ops between same-acc uses
      accs[0][gi] = mfma16(Ah, bq[sl0][0], accs[0][gi]);
      accs[1][gi] = mfma16(Ah, bq[sl0][2], accs[1][gi]);
      accs[0][gi] = mfma16(Ah, bq[sl0][1], accs[0][gi]);
      accs[1][gi] = mfma16(Ah, bq[sl0][3], accs[1][gi]);
      accs[0][gi] = mfma16(Al, bq[sl0][0], accs[0][gi]);
      accs[1][gi] = mfma16(Al, bq[sl0][2], accs[1][gi]);
    }

    // ---- in-register epilogue: gates -> h_new -> hbuf + h_hist
    float visit = (float)t * (1.0f / 511.0f);
#pragma unroll
    for (int qq = 0; qq < 2; ++qq) {
      int jcol = (q0 + qq) * 16 + l15;
#pragma unroll
      for (int r = 0; r < 4; ++r) {
        int m = l4 * 4 + r;
        float lr = accs[qq][0][r] + b2r[qq][r] + visit * wvr[qq];
        float lz = accs[qq][1][r] + b2z[qq][r] + visit * wvz[qq];
        float hn = accs[qq][2][r] + bhn2[qq];
        float xn = accs[qq][3][r] + b2x[qq][r] + visit * wvn[qq];
        float rg = 1.0f / (1.0f + __expf(-lr));
        float zg = 1.0f / (1.0f + __expf(-lz));
        float e2 = __expf(2.0f * (xn + rg * hn));
        float ng = 1.0f - 2.0f / (e2 + 1.0f);
        float hp = hbuf[m][jcol];
        float hv = (1.0f - zg) * ng + zg * hp;
        hbuf[m][jcol] = hv;
        h_hist[((size_t)(bb * 16 + m) * NT + t) * NH + jcol] = hv;
      }
    }
    __syncthreads();
    zv = znext;
  }
#undef BADDR
}

// ---------------- fused temporal heads: temporal_cont, hazards, tcat3, mask -------
__global__ __launch_bounds__(256)
void k_heads(const float* __restrict__ h_hist, const float* __restrict__ tcw,
             const float* __restrict__ tcb, const float* __restrict__ i1w,
             const float* __restrict__ i1b, const float* __restrict__ i2w,
             const float* __restrict__ i2b, const float* __restrict__ tcatw,
             const float* __restrict__ tcatb, float* __restrict__ out,
             float* __restrict__ hazard, uint32_t g2a, uint32_t g2b) {
  int r = blockIdx.x * 256 + threadIdx.x;       // 512 blocks -> 131072 rows
  const float* hr = h_hist + (size_t)r * 256;
  float a[16] = {0.f}; float ai0 = 0.f, ai1 = 0.f; float at[5] = {0.f};
  for (int k4 = 0; k4 < 64; ++k4) {
    float4 hv = *(const float4*)(hr + k4 * 4);
#pragma unroll
    for (int i = 0; i < 16; ++i) {
      float4 wv = *(const float4*)(tcw + i * 256 + k4 * 4);
      a[i] += hv.x * wv.x + hv.y * wv.y + hv.z * wv.z + hv.w * wv.w;
    }
    { float4 wv = *(const float4*)(i1w + k4 * 4); ai0 += hv.x * wv.x + hv.y * wv.y + hv.z * wv.z + hv.w * wv.w; }
    { float4 wv = *(const float4*)(i2w + k4 * 4); ai1 += hv.x * wv.x + hv.y * wv.y + hv.z * wv.z + hv.w * wv.w; }
#pragma unroll
    for (int i = 0; i < 5; ++i) {
      float4 wv = *(const float4*)(tcatw + i * 256 + k4 * 4);
      at[i] += hv.x * wv.x + hv.y * wv.y + hv.z * wv.z + hv.w * wv.w;
    }
  }
  float* o2 = out + OUT_TC + (size_t)r * 16;
#pragma unroll
  for (int i = 0; i < 16; ++i) o2[i] = tanhf(a[i] + tcb[i]) * 0.5f + 0.5f;
  float h0 = 1.0f / (1.0f + expf(-(ai0 + i1b[0])));
  float h1 = 1.0f / (1.0f + expf(-(ai1 + i2b[0])));
  hazard[(size_t)r * 2 + 0] = h0;
  hazard[(size_t)r * 2 + 1] = h1;
  float lg[5];
#pragma unroll
  for (int i = 0; i < 5; ++i) lg[i] = at[i] + tcatb[i] + gumbel_pt(g2a, g2b, (uint32_t)(r * 5 + i));
  float m = lg[0];
#pragma unroll
  for (int i = 1; i < 5; ++i) m = fmaxf(m, lg[i]);
  float e[5], s = 0.f;
#pragma unroll
  for (int i = 0; i < 5; ++i) { e[i] = expf(lg[i] - m); s += e[i]; }
  float* o3 = out + OUT_TCAT + (size_t)r * 9;
#pragma unroll
  for (int i = 0; i < 5; ++i) o3[4 + i] = e[i] / s;
  out[OUT_MASK + r] = 1.0f;
}

// ------- irreversible states, parallel: absorbed_t = prefix-OR(hz>0.5) ----------
// s1_t>0.5 iff s1_{t-1}>0.5 or hz_t>0.5  =>  output at t is "absorbed" iff
// t > tfirst, where tfirst = 0 if init absorbed else min{t>=1: hz_t>0.5}.
__global__ void k_scan(const float* __restrict__ init, const float* __restrict__ hazard,
                       float* __restrict__ out) {
  int w = threadIdx.x >> 6, l = threadIdx.x & 63;
  int task = blockIdx.x * 4 + w;       // grid 128 x 4 waves = 512 = 256 b x 2 var
  int b = task >> 1, var = task & 1;
  float hz[8]; int tmin = 1 << 20;
#pragma unroll
  for (int c = 0; c < 8; ++c) {
    int t = 1 + c * 64 + l;
    hz[c] = 0.0f;
    if (t < NT) {
      hz[c] = hazard[((size_t)b * NT + t) * 2 + var];
      if (hz[c] > 0.5f) tmin = min(tmin, t);
    }
  }
#pragma unroll
  for (int m = 32; m > 0; m >>= 1) tmin = min(tmin, __shfl_xor(tmin, m));
  float s1i = init[b * 4 + var * 2 + 1];
  if (s1i > 0.5f) tmin = 0;
  float* tc = out + OUT_TCAT + (size_t)b * NT * 9 + var * 2;
  if (l == 0) { tc[0] = init[b * 4 + var * 2]; tc[1] = s1i; }
#pragma unroll
  for (int c = 0; c < 8; ++c) {
    int t = 1 + c * 64 + l;
    if (t < NT) {
      bool ab = t > tmin;
      float s1 = ab ? 1.0f : hz[c];
      float s0 = ab ? 0.0f : 1.0f - hz[c];
      tc[(size_t)t * 9 + 0] = s0;
      tc[(size_t)t * 9 + 1] = s1;
    }
  }
}

// =============================== launch ===============================
extern "C" void kernel_launch(void* const* d_in, const int* in_sizes, int n_in,
                              void* d_out, int out_size, void* d_ws, size_t ws_size,
                              hipStream_t stream) {
  (void)in_sizes; (void)n_in; (void)out_size; (void)ws_size;
  const float* z_static = (const float*)d_in[0];
  const float* z_temporal = (const float*)d_in[1];
  const float* initial_states = (const float*)d_in[2];
  const float* sn_w1 = (const float*)d_in[3];
  const float* sn_b1 = (const float*)d_in[4];
  const float* bn1_g = (const float*)d_in[5];
  const float* bn1_b = (const float*)d_in[6];
  const float* sn_w2 = (const float*)d_in[7];
  const float* sn_b2 = (const float*)d_in[8];
  const float* bn2_g = (const float*)d_in[9];
  const float* bn2_b = (const float*)d_in[10];
  const float* sc_w = (const float*)d_in[11];
  const float* sc_b = (const float*)d_in[12];
  const float* scat1_w = (const float*)d_in[13];
  const float* scat1_b = (const float*)d_in[14];
  const float* scat2_w = (const float*)d_in[15];
  const float* scat2_b = (const float*)d_in[16];
  const float* gru_wih = (const float*)d_in[17];
  const float* gru_whh = (const float*)d_in[18];
  const float* gru_bih = (const float*)d_in[19];
  const float* gru_bhh = (const float*)d_in[20];
  const float* tc_w = (const float*)d_in[21];
  const float* tc_b = (const float*)d_in[22];
  const float* irr1_w = (const float*)d_in[23];
  const float* irr1_b = (const float*)d_in[24];
  const float* irr2_w = (const float*)d_in[25];
  const float* irr2_b = (const float*)d_in[26];
  const float* tcat_w = (const float*)d_in[27];
  const float* tcat_b = (const float*)d_in[28];

  float* out = (float*)d_out;
  float* ws = (float*)d_ws;
  float* bl1 = ws + WS_BL1;
  float* baseline = ws + WS_BASE;
  float* bias2 = ws + WS_BIAS;
  float* h_hist = ws + WS_HHIST;
  float* hazard = ws + WS_HAZ;
  uint16_t* bfrag = (uint16_t*)(ws + WS_BFRAG);

  // JAX gk = split(key(42), 3), partitionable foldlike: gk[i] = block((0,42),(0,i))
  uint32_t gk[3][2];
  for (uint32_t i = 0; i < 3; ++i) {
    uint32_t a = 0u, b = i;
    tf2x32(0u, 42u, a, b);
    gk[i][0] = a; gk[i][1] = b;
  }

  k_prep<<<240, 256, 0, stream>>>(gru_whh, gru_wih, bfrag);
  k_static<<<256, 256, 0, stream>>>(z_static, 64, sn_w1, sn_b1, bn1_g, bn1_b, bl1);
  k_static<<<256, 256, 0, stream>>>(bl1, 256, sn_w2, sn_b2, bn2_g, bn2_b, baseline);
  k_bias<<<256, 256, 0, stream>>>(baseline, initial_states, gru_wih, gru_bih, gru_bhh, bias2);
  k_sheads<<<256, 64, 0, stream>>>(baseline, sc_w, sc_b, scat1_w, scat1_b, scat2_w, scat2_b,
                                   out, gk[0][0], gk[0][1], gk[1][0], gk[1][1]);

  k_persist<<<16, 512, 0, stream>>>(z_temporal, bfrag, bias2, gru_wih, gru_bhh, h_hist);

  k_heads<<<512, 256, 0, stream>>>(h_hist, tc_w, tc_b, irr1_w, irr1_b, irr2_w, irr2_b,
                                   tcat_w, tcat_b, out, hazard, gk[2][0], gk[2][1]);
  k_scan<<<128, 256, 0, stream>>>(initial_states, hazard, out);
}